// Round 2
// baseline (114.834 us; speedup 1.0000x reference)
//
#include <hip/hip_runtime.h>

// Per-token head-attention: B*S = 8192 independent tokens, each:
//   S = Q K^T / sqrt(128) (32x32 over heads), P = softmax, O = P V (32x128).
// One wave = one token. Latency-hiding version: all Q/K loads hoisted into
// live registers; V staged to LDS via fire-and-forget global_load_lds.

typedef __bf16 bf16x8 __attribute__((ext_vector_type(8)));
typedef __bf16 bf16x2 __attribute__((ext_vector_type(2)));
typedef float  f32x4  __attribute__((ext_vector_type(4)));

static constexpr float kScale = 0.08838834764831845f;  // 1/sqrt(128)

typedef const __attribute__((address_space(1))) unsigned int* gas_ptr;
typedef __attribute__((address_space(3))) unsigned int* las_ptr;

__device__ inline bf16x8 to_bf16x8(f32x4 a, f32x4 b) {
  bf16x8 f;
  f[0] = (__bf16)a[0]; f[1] = (__bf16)a[1];
  f[2] = (__bf16)a[2]; f[3] = (__bf16)a[3];
  f[4] = (__bf16)b[0]; f[5] = (__bf16)b[1];
  f[6] = (__bf16)b[2]; f[7] = (__bf16)b[3];
  return f;
}

__global__ __launch_bounds__(256, 2) void attn_headwise(
    const float* __restrict__ q, const float* __restrict__ k,
    const float* __restrict__ v, float* __restrict__ out, int ntok) {
  const int wave = threadIdx.x >> 6;
  const int lane = threadIdx.x & 63;
  const int lr   = lane & 15;
  const int G    = lane >> 4;

  const long token = (long)blockIdx.x * 4 + wave;
  if (token >= ntok) return;
  const float* qt = q + token * 4096;
  const float* kt = k + token * 4096;
  const float* vt = v + token * 4096;
  float*       ot = out + token * 4096;

  __shared__ __align__(16) float        vbuf[4][32 * 128];  // 64 KB (f32 V)
  __shared__ __align__(16) unsigned int pbuf[4][32 * 16];   //  8 KB (bf16 P)
  float*        vl = vbuf[wave];
  unsigned int* pl = pbuf[wave];

  // ---- 1) issue ALL Q/K loads into live registers (max MLP) -------------
  f32x4 kraw[4][2][2], qraw[4][2][2];
  #pragma unroll
  for (int kk = 0; kk < 4; ++kk)
    #pragma unroll
    for (int t = 0; t < 2; ++t) {
      const float* pk = kt + (16 * t + lr) * 128 + 32 * kk + 8 * G;
      kraw[kk][t][0] = *(const f32x4*)pk;
      kraw[kk][t][1] = *(const f32x4*)(pk + 4);
      const float* pq = qt + (16 * t + lr) * 128 + 32 * kk + 8 * G;
      qraw[kk][t][0] = *(const f32x4*)pq;
      qraw[kk][t][1] = *(const f32x4*)(pq + 4);
    }

  // ---- 2) fire-and-forget V staging into LDS (16 KB, f32, linear) -------
  {
    const float* vsrc = vt + lane * 4;
    #pragma unroll
    for (int i = 0; i < 16; ++i)
      __builtin_amdgcn_global_load_lds((gas_ptr)(vsrc + i * 256),
                                       (las_ptr)(vl + i * 256), 16, 0, 0);
  }

  // ---- 3) S^T[g][h] = sum_d K[g][d] Q[h][d] ------------------------------
  f32x4 acc[2][2];
  acc[0][0] = 0.f; acc[0][1] = 0.f; acc[1][0] = 0.f; acc[1][1] = 0.f;
  #pragma unroll
  for (int kk = 0; kk < 4; ++kk) {
    bf16x8 af[2], bq[2];
    #pragma unroll
    for (int t = 0; t < 2; ++t) {
      af[t] = to_bf16x8(kraw[kk][t][0], kraw[kk][t][1]);
      bq[t] = to_bf16x8(qraw[kk][t][0], qraw[kk][t][1]);
    }
    #pragma unroll
    for (int gi = 0; gi < 2; ++gi)
      #pragma unroll
      for (int hj = 0; hj < 2; ++hj)
        acc[gi][hj] = __builtin_amdgcn_mfma_f32_16x16x32_bf16(
            af[gi], bq[hj], acc[gi][hj], 0, 0, 0);
  }

  // ---- 4) softmax over g (rows of S^T), per column h ---------------------
  #pragma unroll
  for (int hj = 0; hj < 2; ++hj) {
    float m = acc[0][hj][0];
    #pragma unroll
    for (int gi = 0; gi < 2; ++gi)
      #pragma unroll
      for (int r = 0; r < 4; ++r) m = fmaxf(m, acc[gi][hj][r]);
    m = fmaxf(m, __shfl_xor(m, 16, 64));
    m = fmaxf(m, __shfl_xor(m, 32, 64));

    float pv[2][4];
    float s = 0.f;
    #pragma unroll
    for (int gi = 0; gi < 2; ++gi)
      #pragma unroll
      for (int r = 0; r < 4; ++r) {
        float e = __expf((acc[gi][hj][r] - m) * kScale);
        pv[gi][r] = e;
        s += e;
      }
    s += __shfl_xor(s, 16, 64);
    s += __shfl_xor(s, 32, 64);
    float inv = 1.0f / s;

    #pragma unroll
    for (int gi = 0; gi < 2; ++gi)
      #pragma unroll
      for (int mp = 0; mp < 2; ++mp) {
        bf16x2 t;
        t[0] = (__bf16)(pv[gi][2 * mp]     * inv);
        t[1] = (__bf16)(pv[gi][2 * mp + 1] * inv);
        pl[(16 * hj + lr) * 16 + 8 * gi + 2 * G + mp] =
            __builtin_bit_cast(unsigned int, t);
      }
  }

  // ---- 5) read P fragments (B-operand) -----------------------------------
  bf16x8 pf[2];
  #pragma unroll
  for (int ht = 0; ht < 2; ++ht)
    pf[ht] = *(const bf16x8*)&pl[(16 * ht + lr) * 16 + 4 * G];

  // ---- 6) wait for V staging, then O^T = V^T P^T --------------------------
  asm volatile("s_waitcnt vmcnt(0)" ::: "memory");
  f32x4 zero = 0.f;
  #pragma unroll
  for (int dt = 0; dt < 8; ++dt) {
    bf16x8 vf;
    #pragma unroll
    for (int e = 0; e < 8; ++e)
      vf[e] = (__bf16)vl[(8 * G + e) * 128 + 16 * dt + lr];
    f32x4 o0 = __builtin_amdgcn_mfma_f32_16x16x32_bf16(vf, pf[0], zero, 0, 0, 0);
    f32x4 o1 = __builtin_amdgcn_mfma_f32_16x16x32_bf16(vf, pf[1], zero, 0, 0, 0);
    *(f32x4*)&ot[lr * 128 + 16 * dt + 4 * G]        = o0;
    *(f32x4*)&ot[(16 + lr) * 128 + 16 * dt + 4 * G] = o1;
  }
}

extern "C" void kernel_launch(void* const* d_in, const int* in_sizes, int n_in,
                              void* d_out, int out_size, void* d_ws, size_t ws_size,
                              hipStream_t stream) {
  const float* q = (const float*)d_in[0];
  const float* k = (const float*)d_in[1];
  const float* v = (const float*)d_in[2];
  float* out = (float*)d_out;
  int ntok = in_sizes[0] / 4096;   // B*S tokens (H*D = 4096 floats per token)
  int grid = (ntok + 3) / 4;       // 4 waves (tokens) per 256-thread block
  hipLaunchKernelGGL(attn_headwise, dim3(grid), dim3(256), 0, stream,
                     q, k, v, out, ntok);
}

// Round 3
// 111.812 us; speedup vs baseline: 1.0270x; 1.0270x over previous
//
#include <hip/hip_runtime.h>

// Per-token head-attention: B*S = 8192 independent tokens, each:
//   S = Q K^T / sqrt(128) (32x32 over heads), P = softmax, O = P V (32x128).
// One wave = one token. Latency-hiding version: all Q/K loads hoisted into
// live registers; V staged to LDS via fire-and-forget global_load_lds.

typedef __bf16 bf16x8 __attribute__((ext_vector_type(8)));
typedef __bf16 bf16x2 __attribute__((ext_vector_type(2)));
typedef float  f32x4  __attribute__((ext_vector_type(4)));

static constexpr float kScale = 0.08838834764831845f;  // 1/sqrt(128)

typedef const __attribute__((address_space(1))) unsigned int* gas_ptr;
typedef __attribute__((address_space(3))) unsigned int* las_ptr;

__device__ inline bf16x8 to_bf16x8(f32x4 a, f32x4 b) {
  bf16x8 f;
  f[0] = (__bf16)a[0]; f[1] = (__bf16)a[1];
  f[2] = (__bf16)a[2]; f[3] = (__bf16)a[3];
  f[4] = (__bf16)b[0]; f[5] = (__bf16)b[1];
  f[6] = (__bf16)b[2]; f[7] = (__bf16)b[3];
  return f;
}

__global__ __launch_bounds__(256, 2) void attn_headwise(
    const float* __restrict__ q, const float* __restrict__ k,
    const float* __restrict__ v, float* __restrict__ out, int ntok) {
  const int wave = threadIdx.x >> 6;
  const int lane = threadIdx.x & 63;
  const int lr   = lane & 15;
  const int G    = lane >> 4;

  const long token = (long)blockIdx.x * 4 + wave;
  if (token >= ntok) return;
  const float* qt = q + token * 4096;
  const float* kt = k + token * 4096;
  const float* vt = v + token * 4096;
  float*       ot = out + token * 4096;

  __shared__ __align__(16) float        vbuf[4][32 * 128];  // 64 KB (f32 V)
  __shared__ __align__(16) unsigned int pbuf[4][32 * 16];   //  8 KB (bf16 P)
  float*        vl = vbuf[wave];
  unsigned int* pl = pbuf[wave];

  // ---- 1) issue ALL Q/K loads into live registers (max MLP) -------------
  f32x4 kraw[4][2][2], qraw[4][2][2];
  #pragma unroll
  for (int kk = 0; kk < 4; ++kk)
    #pragma unroll
    for (int t = 0; t < 2; ++t) {
      const float* pk = kt + (16 * t + lr) * 128 + 32 * kk + 8 * G;
      kraw[kk][t][0] = *(const f32x4*)pk;
      kraw[kk][t][1] = *(const f32x4*)(pk + 4);
      const float* pq = qt + (16 * t + lr) * 128 + 32 * kk + 8 * G;
      qraw[kk][t][0] = *(const f32x4*)pq;
      qraw[kk][t][1] = *(const f32x4*)(pq + 4);
    }

  // ---- 2) fire-and-forget V staging into LDS (16 KB, f32, linear) -------
  {
    const float* vsrc = vt + lane * 4;
    #pragma unroll
    for (int i = 0; i < 16; ++i)
      __builtin_amdgcn_global_load_lds((gas_ptr)(vsrc + i * 256),
                                       (las_ptr)(vl + i * 256), 16, 0, 0);
  }

  // ---- 3) S^T[g][h] = sum_d K[g][d] Q[h][d] ------------------------------
  f32x4 acc[2][2];
  acc[0][0] = 0.f; acc[0][1] = 0.f; acc[1][0] = 0.f; acc[1][1] = 0.f;
  #pragma unroll
  for (int kk = 0; kk < 4; ++kk) {
    bf16x8 af[2], bq[2];
    #pragma unroll
    for (int t = 0; t < 2; ++t) {
      af[t] = to_bf16x8(kraw[kk][t][0], kraw[kk][t][1]);
      bq[t] = to_bf16x8(qraw[kk][t][0], qraw[kk][t][1]);
    }
    #pragma unroll
    for (int gi = 0; gi < 2; ++gi)
      #pragma unroll
      for (int hj = 0; hj < 2; ++hj)
        acc[gi][hj] = __builtin_amdgcn_mfma_f32_16x16x32_bf16(
            af[gi], bq[hj], acc[gi][hj], 0, 0, 0);
  }

  // ---- 4) softmax over g (rows of S^T), per column h ---------------------
  #pragma unroll
  for (int hj = 0; hj < 2; ++hj) {
    float m = acc[0][hj][0];
    #pragma unroll
    for (int gi = 0; gi < 2; ++gi)
      #pragma unroll
      for (int r = 0; r < 4; ++r) m = fmaxf(m, acc[gi][hj][r]);
    m = fmaxf(m, __shfl_xor(m, 16, 64));
    m = fmaxf(m, __shfl_xor(m, 32, 64));

    float pv[2][4];
    float s = 0.f;
    #pragma unroll
    for (int gi = 0; gi < 2; ++gi)
      #pragma unroll
      for (int r = 0; r < 4; ++r) {
        float e = __expf((acc[gi][hj][r] - m) * kScale);
        pv[gi][r] = e;
        s += e;
      }
    s += __shfl_xor(s, 16, 64);
    s += __shfl_xor(s, 32, 64);
    float inv = 1.0f / s;

    #pragma unroll
    for (int gi = 0; gi < 2; ++gi)
      #pragma unroll
      for (int mp = 0; mp < 2; ++mp) {
        bf16x2 t;
        t[0] = (__bf16)(pv[gi][2 * mp]     * inv);
        t[1] = (__bf16)(pv[gi][2 * mp + 1] * inv);
        pl[(16 * hj + lr) * 16 + 8 * gi + 2 * G + mp] =
            __builtin_bit_cast(unsigned int, t);
      }
  }

  // ---- 5) read P fragments (B-operand) -----------------------------------
  bf16x8 pf[2];
  #pragma unroll
  for (int ht = 0; ht < 2; ++ht)
    pf[ht] = *(const bf16x8*)&pl[(16 * ht + lr) * 16 + 4 * G];

  // ---- 6) wait for V staging, then O^T = V^T P^T --------------------------
  asm volatile("s_waitcnt vmcnt(0)" ::: "memory");
  f32x4 zero = 0.f;
  #pragma unroll
  for (int dt = 0; dt < 8; ++dt) {
    bf16x8 vf;
    #pragma unroll
    for (int e = 0; e < 8; ++e)
      vf[e] = (__bf16)vl[(8 * G + e) * 128 + 16 * dt + lr];
    f32x4 o0 = __builtin_amdgcn_mfma_f32_16x16x32_bf16(vf, pf[0], zero, 0, 0, 0);
    f32x4 o1 = __builtin_amdgcn_mfma_f32_16x16x32_bf16(vf, pf[1], zero, 0, 0, 0);
    *(f32x4*)&ot[lr * 128 + 16 * dt + 4 * G]        = o0;
    *(f32x4*)&ot[(16 + lr) * 128 + 16 * dt + 4 * G] = o1;
  }
}

extern "C" void kernel_launch(void* const* d_in, const int* in_sizes, int n_in,
                              void* d_out, int out_size, void* d_ws, size_t ws_size,
                              hipStream_t stream) {
  const float* q = (const float*)d_in[0];
  const float* k = (const float*)d_in[1];
  const float* v = (const float*)d_in[2];
  float* out = (float*)d_out;
  int ntok = in_sizes[0] / 4096;   // B*S tokens (H*D = 4096 floats per token)
  int grid = (ntok + 3) / 4;       // 4 waves (tokens) per 256-thread block
  hipLaunchKernelGGL(attn_headwise, dim3(grid), dim3(256), 0, stream,
                     q, k, v, out, ntok);
}